// Round 1
// baseline (20965.555 us; speedup 1.0000x reference)
//
#include <hip/hip_runtime.h>

// AugmentedLstm: B=16, T=2048, D=H=512.
// Single persistent cooperative kernel: 64 WGs x 256 threads, one grid
// barrier per timestep (monotonic counter in d_ws), weights as MFMA
// B-fragments in registers, f16 16x16x32 MFMA for the recurrent GEMM.
//
// Math: g = (x_t + h)@Wt[:, :5H] + 2b  (pi and ps share W)
//       pi5 = (x+h)@W5 - h@W5 + b5     (highway input, no precompute GEMM)

#define NG 64      // workgroups (grid barrier participants)
#define BLK 256    // threads per WG (4 waves)
#define BB 16      // batch
#define TT 2048    // timesteps
#define DD 512     // input dim
#define HHH 512    // hidden dim
#define CC 8       // output columns per gate per WG (HHH / NG)

typedef _Float16 f16;
typedef _Float16 f16x4 __attribute__((ext_vector_type(4)));
typedef _Float16 f16x8 __attribute__((ext_vector_type(8)));
typedef float f32x4 __attribute__((ext_vector_type(4)));

__device__ __forceinline__ float sigf(float v) {
  return 1.0f / (1.0f + __expf(-v));
}
__device__ __forceinline__ float tanhfast(float v) {
  return 2.0f / (1.0f + __expf(-2.0f * v)) - 1.0f;
}

__global__ __launch_bounds__(BLK, 1) void lstm_scan(
    const float* __restrict__ x, const int* __restrict__ lengths,
    const float* __restrict__ W, const float* __restrict__ bias,
    float* __restrict__ out, unsigned* __restrict__ cnt,
    f16* __restrict__ hex /* double-buffered h exchange: [2][BB*HHH] f16 */) {
  __shared__ f16 u_sw[BB * DD];          // u = x+h, pre-swizzled A-frag order
  __shared__ f16 h_sw[BB * DD];          // h alone, same order (for h@W5)
  __shared__ float gbuf[4 * 16 * 17];    // per-tile MFMA results (pad 17)
  __shared__ float cbuf[BB * CC];        // cell state, private to WG

  const int tid = threadIdx.x;
  const int wg = blockIdx.x;
  const int wave = tid >> 6;
  const int lane = tid & 63;
  const int q = lane >> 4;    // quad
  const int n16 = lane & 15;  // tile column

  // ---- Weight B-fragments in registers (loaded once).
  // Tiles 0..2: A=u, 16 cols each = gates {0,1},{2,3},{4,5} x 8 cols.
  // Tile  3   : A=h, cols 0..7 = gate-5 rows (Q = h@W5), cols 8..15 zero.
  // B-frag: lane holds B[k = kk*32 + q*8 + j][n = lane&15]; B[k][n] =
  // Wt[k][col] = W_in[row(col)][k]  (W_in row is contiguous in k).
  f16x8 bW[16];
  {
    int grow = 0;
    bool valid = true;
    if (wave < 3) {
      int gate = 2 * wave + (n16 >> 3);
      grow = gate * HHH + wg * CC + (n16 & 7);
    } else if (n16 < 8) {
      grow = 5 * HHH + wg * CC + n16;
    } else {
      valid = false;
    }
    const float* wr = W + (size_t)grow * DD;
#pragma unroll
    for (int kk = 0; kk < 16; ++kk) {
      f16x8 v;
      if (valid) {
        const float* p = wr + kk * 32 + q * 8;
#pragma unroll
        for (int j = 0; j < 8; ++j) v[j] = (f16)p[j];
      } else {
#pragma unroll
        for (int j = 0; j < 8; ++j) v[j] = (f16)0.0f;
      }
      bW[kk] = v;
    }
  }

  // ---- Staging index precompute. Thread i-th chunk covers elements
  // e..e+3 of the flat [m][k] (16x512) matrix; written to LDS in exact
  // fragment order: f16 offset (kk*64 + q*16 + m)*8 + j  -> lane L reads
  // one contiguous 16B ds_read_b128 at (kk*64 + L)*8.
  int soffv[8], eoffv[8];
  size_t xcm[8];
#pragma unroll
  for (int i = 0; i < 8; ++i) {
    int e = (tid + i * BLK) * 4;
    int m = e >> 9;
    int k = e & 511;
    eoffv[i] = e;                       // hex is flat [m*512 + k] == e
    xcm[i] = (size_t)m * TT * DD + k;   // x[b=m][t][k] base (add t*DD)
    int kk = k >> 5, qq = (k >> 3) & 3, j0 = k & 7;
    soffv[i] = (kk * 64 + qq * 16 + m) * 8 + j0;
  }

  // ---- Epilogue constants (threads 0..127: b = tid>>3, n = tid&7).
  const int eb = tid >> 3;
  const int en = tid & 7;
  float bb0 = 0, bb1 = 0, bb2 = 0, bb3 = 0, bb4 = 0, bb5 = 0;
  int mylen = 0;
  if (tid < 128) {
    int gc = wg * CC + en;
    bb0 = bias[0 * HHH + gc];
    bb1 = bias[1 * HHH + gc];
    bb2 = bias[2 * HHH + gc];
    bb3 = bias[3 * HHH + gc];
    bb4 = bias[4 * HHH + gc];
    bb5 = bias[5 * HHH + gc];
    mylen = lengths[eb];
    cbuf[tid] = 0.0f;  // c0 = 0
  }

  // Prefetch x(t=0).
  f32x4 xv[8];
#pragma unroll
  for (int i = 0; i < 8; ++i) xv[i] = *(const f32x4*)(x + xcm[i]);

  __syncthreads();

  for (int t = 0; t < TT; ++t) {
    // ---- Stage u = f16(x) + h and h into LDS (swizzled).
    const f16* hr = hex + (size_t)(t & 1) * (BB * HHH);
#pragma unroll
    for (int i = 0; i < 8; ++i) {
      f16x4 hv = *(const f16x4*)(hr + eoffv[i]);
      f16x4 uv;
#pragma unroll
      for (int j = 0; j < 4; ++j) uv[j] = (f16)xv[i][j] + hv[j];
      *(f16x4*)(u_sw + soffv[i]) = uv;
      *(f16x4*)(h_sw + soffv[i]) = hv;
    }
    __syncthreads();

    // ---- MFMA: each wave runs one 16-col tile, K = 512 (16 steps).
    f32x4 acc = {0.f, 0.f, 0.f, 0.f};
    const f16* asrc = (wave < 3) ? u_sw : h_sw;
#pragma unroll
    for (int kk = 0; kk < 16; ++kk) {
      f16x8 a = *(const f16x8*)(asrc + (kk * 64 + lane) * 8);
      acc = __builtin_amdgcn_mfma_f32_16x16x32_f16(a, bW[kk], acc, 0, 0, 0);
    }
    // C/D layout: col = lane&15, row(b) = q*4 + r.
#pragma unroll
    for (int r = 0; r < 4; ++r)
      gbuf[wave * 272 + (q * 4 + r) * 17 + n16] = acc[r];
    __syncthreads();

    // ---- Epilogue (fp32): gates, cell, highway, mask, publish h'.
    if (tid < 128) {
      float g0 = gbuf[0 * 272 + eb * 17 + en] + 2.f * bb0;      // i
      float g1 = gbuf[0 * 272 + eb * 17 + en + 8] + 2.f * bb1;  // f
      float g2 = gbuf[1 * 272 + eb * 17 + en] + 2.f * bb2;      // m~
      float g3 = gbuf[1 * 272 + eb * 17 + en + 8] + 2.f * bb3;  // o
      float g4 = gbuf[2 * 272 + eb * 17 + en] + 2.f * bb4;      // hw
      float p5 = gbuf[2 * 272 + eb * 17 + en + 8];              // (x+h)@W5
      float qv = gbuf[3 * 272 + eb * 17 + en];                  // h@W5
      float ig = sigf(g0), fg = sigf(g1), mt = tanhfast(g2);
      float og = sigf(g3), hwv = sigf(g4);
      float pi5 = p5 - qv + bb5;  // x@W5 + b5
      float cold = cbuf[tid];
      float mem = ig * mt + fg * cold;
      float o1 = og * tanhfast(mem);
      float ov = hwv * o1 + (1.0f - hwv) * pi5;
      float msk = (t < mylen) ? 1.0f : 0.0f;
      ov *= msk;
      mem *= msk;
      cbuf[tid] = mem;
      out[((size_t)eb * TT + t) * HHH + wg * CC + en] = ov;
      hex[(size_t)((t + 1) & 1) * (BB * HHH) + eb * HHH + wg * CC + en] =
          (f16)ov;
    }

    // ---- Publish + grid barrier (one per step).
    __threadfence();  // make hex/out stores device-visible (agent scope)

    // Prefetch x(t+1) after the fence so the loads fly during the barrier.
    if (t + 1 < TT) {
#pragma unroll
      for (int i = 0; i < 8; ++i)
        xv[i] = *(const f32x4*)(x + xcm[i] + (size_t)(t + 1) * DD);
    }

    __syncthreads();
    if (tid == 0) {
      __hip_atomic_fetch_add(cnt, 1u, __ATOMIC_RELEASE,
                             __HIP_MEMORY_SCOPE_AGENT);
      const unsigned target = (unsigned)(t + 1) * NG;
      while (__hip_atomic_load(cnt, __ATOMIC_ACQUIRE,
                               __HIP_MEMORY_SCOPE_AGENT) < target) {
        __builtin_amdgcn_s_sleep(1);
      }
    }
    __syncthreads();
  }
}

extern "C" void kernel_launch(void* const* d_in, const int* in_sizes, int n_in,
                              void* d_out, int out_size, void* d_ws,
                              size_t ws_size, hipStream_t stream) {
  (void)in_sizes;
  (void)n_in;
  (void)out_size;
  (void)ws_size;
  const float* x = (const float*)d_in[0];
  const int* lengths = (const int*)d_in[1];
  const float* W = (const float*)d_in[2];
  const float* bias = (const float*)d_in[3];
  float* out = (float*)d_out;

  unsigned* cnt = (unsigned*)d_ws;                 // barrier counter
  f16* hex = (f16*)((char*)d_ws + 256);            // [2][16*512] f16
  const size_t init_bytes = 256 + 2 * BB * HHH * sizeof(f16);
  hipMemsetAsync(d_ws, 0, init_bytes, stream);     // cnt=0, h0=0

  lstm_scan<<<dim3(NG), dim3(BLK), 0, stream>>>(x, lengths, W, bias, out, cnt,
                                                hex);
}

// Round 2
// 10027.469 us; speedup vs baseline: 2.0908x; 2.0908x over previous
//
#include <hip/hip_runtime.h>

// AugmentedLstm: B=16, T=2048, D=H=512.
// 64 persistent WGs x 256 threads. NO grid barrier: h' is published as
// packed u64 agent-scope relaxed atomics {2 x f16, u32 step-tag}; consumers
// poll the tag. Two parity buffers; dataflow bounds WG skew to 1 step, so
// overwrite-before-read cannot happen. LDS staging XOR-swizzled by kk to
// kill the 16-way ds_write bank conflicts of round 1.
//
// Math: g = (x_t + h)@Wt[:, :5H] + 2b  (pi and ps share W)
//       pi5 = (x+h)@W5 - h@W5 + b5     (highway input)

#define NG 64
#define BLK 256
#define BB 16
#define TT 2048
#define DD 512
#define HHH 512
#define CC 8

typedef _Float16 f16;
typedef _Float16 f16x4 __attribute__((ext_vector_type(4)));
typedef _Float16 f16x8 __attribute__((ext_vector_type(8)));
typedef float f32x4 __attribute__((ext_vector_type(4)));
typedef unsigned long long u64;

__device__ __forceinline__ float sigf(float v) {
  return 1.0f / (1.0f + __expf(-v));
}
__device__ __forceinline__ float tanhfast(float v) {
  return 2.0f / (1.0f + __expf(-2.0f * v)) - 1.0f;
}

__device__ __forceinline__ f16 h_lo(u64 w) {
  return __builtin_bit_cast(f16, (unsigned short)(w & 0xffffu));
}
__device__ __forceinline__ f16 h_hi(u64 w) {
  return __builtin_bit_cast(f16, (unsigned short)((w >> 16) & 0xffffu));
}

__global__ __launch_bounds__(BLK, 1) void lstm_scan(
    const float* __restrict__ x, const int* __restrict__ lengths,
    const float* __restrict__ W, const float* __restrict__ bias,
    float* __restrict__ out, u64* __restrict__ hex /* [2][16][256] tagged */) {
  __shared__ f16 u_sw[BB * DD];        // u = x+h, swizzled A-frag order
  __shared__ f16 h_sw[BB * DD];        // h alone (for h@W5)
  __shared__ float gbuf[4 * 16 * 17];  // per-tile MFMA results
  __shared__ float cbuf[BB * CC];      // cell state
  __shared__ f16 obuf[BB * CC];        // h' staging for packing

  const int tid = threadIdx.x;
  const int wg = blockIdx.x;
  const int wave = tid >> 6;
  const int lane = tid & 63;
  const int q = lane >> 4;
  const int n16 = lane & 15;

  // ---- Weight B-fragments in registers (loaded once).
  // Tiles 0..2: A=u, 16 cols = gates {0,1},{2,3},{4,5} x 8 cols.
  // Tile  3   : A=h, cols 0..7 = gate-5 rows (h@W5), cols 8..15 zero.
  f16x8 bW[16];
  {
    int grow = 0;
    bool valid = true;
    if (wave < 3) {
      int gate = 2 * wave + (n16 >> 3);
      grow = gate * HHH + wg * CC + (n16 & 7);
    } else if (n16 < 8) {
      grow = 5 * HHH + wg * CC + n16;
    } else {
      valid = false;
    }
    const float* wr = W + (size_t)grow * DD;
#pragma unroll
    for (int kk = 0; kk < 16; ++kk) {
      f16x8 v;
      if (valid) {
        const float* p = wr + kk * 32 + q * 8;
#pragma unroll
        for (int j = 0; j < 8; ++j) v[j] = (f16)p[j];
      } else {
#pragma unroll
        for (int j = 0; j < 8; ++j) v[j] = (f16)0.0f;
      }
      bW[kk] = v;
    }
  }

  // ---- Staging indices. Thread's i-th chunk = cols k..k+3 of row m of the
  // flat [16][512] matrix. LDS granule (8 f16): logical (kk*64 + L),
  // physical (kk*64 + (L ^ kk)) — XOR swizzle makes write banks
  // 4*((m^kk)&7) + (k&4)/2: 16 distinct bank-pairs, minimal 4-phase.
  int soffv[8], pidx[8];
  size_t xcm[8];
#pragma unroll
  for (int i = 0; i < 8; ++i) {
    int e = (tid + i * BLK) * 4;
    int m = e >> 9;
    int k = e & 511;
    pidx[i] = m * 256 + (k >> 1);      // u64 pair index (k multiple of 4)
    xcm[i] = (size_t)m * TT * DD + k;  // x[b=m][t][k] base
    int kk = k >> 5, qq = (k >> 3) & 3, j0 = k & 7;
    int L = qq * 16 + m;
    soffv[i] = (kk * 64 + (L ^ kk)) * 8 + j0;
  }

  // ---- Epilogue constants (threads 0..127: b = tid>>3, n = tid&7).
  const int eb = tid >> 3;
  const int en = tid & 7;
  float bb0 = 0, bb1 = 0, bb2 = 0, bb3 = 0, bb4 = 0, bb5 = 0;
  int mylen = 0;
  if (tid < 128) {
    int gc = wg * CC + en;
    bb0 = bias[0 * HHH + gc];
    bb1 = bias[1 * HHH + gc];
    bb2 = bias[2 * HHH + gc];
    bb3 = bias[3 * HHH + gc];
    bb4 = bias[4 * HHH + gc];
    bb5 = bias[5 * HHH + gc];
    mylen = lengths[eb];
    cbuf[tid] = 0.0f;
  }

  // Prefetch x(t=0).
  f32x4 xv[8];
#pragma unroll
  for (int i = 0; i < 8; ++i) xv[i] = *(const f32x4*)(x + xcm[i]);

  __syncthreads();

  for (int t = 0; t < TT; ++t) {
    // ---- Poll h(t): tag == t in parity slot t&1. First pass issues all 16
    // loads (latency overlapped); second pass respins stragglers.
    const u64* hb = hex + (size_t)(t & 1) * 4096;
    u64 w0[8], w1[8];
#pragma unroll
    for (int i = 0; i < 8; ++i) {
      w0[i] = __hip_atomic_load(hb + pidx[i], __ATOMIC_RELAXED,
                                __HIP_MEMORY_SCOPE_AGENT);
      w1[i] = __hip_atomic_load(hb + pidx[i] + 1, __ATOMIC_RELAXED,
                                __HIP_MEMORY_SCOPE_AGENT);
    }
    const unsigned wtag = (unsigned)t;
#pragma unroll
    for (int i = 0; i < 8; ++i) {
      while ((unsigned)(w0[i] >> 32) != wtag)
        w0[i] = __hip_atomic_load(hb + pidx[i], __ATOMIC_RELAXED,
                                  __HIP_MEMORY_SCOPE_AGENT);
      while ((unsigned)(w1[i] >> 32) != wtag)
        w1[i] = __hip_atomic_load(hb + pidx[i] + 1, __ATOMIC_RELAXED,
                                  __HIP_MEMORY_SCOPE_AGENT);
    }

    // ---- Stage u = f16(x)+h and h into LDS (swizzled, conflict-minimal).
#pragma unroll
    for (int i = 0; i < 8; ++i) {
      f16x4 hv;
      hv[0] = h_lo(w0[i]);
      hv[1] = h_hi(w0[i]);
      hv[2] = h_lo(w1[i]);
      hv[3] = h_hi(w1[i]);
      f16x4 uv;
#pragma unroll
      for (int j = 0; j < 4; ++j) uv[j] = (f16)xv[i][j] + hv[j];
      *(f16x4*)(u_sw + soffv[i]) = uv;
      *(f16x4*)(h_sw + soffv[i]) = hv;
    }
    __syncthreads();

    // ---- MFMA: wave's 16-col tile, K=512, 2 independent chains.
    f32x4 acc0 = {0.f, 0.f, 0.f, 0.f}, acc1 = {0.f, 0.f, 0.f, 0.f};
    const f16* asrc = (wave < 3) ? u_sw : h_sw;
#pragma unroll
    for (int kk = 0; kk < 16; kk += 2) {
      f16x8 a0 = *(const f16x8*)(asrc + (kk * 64 + (lane ^ kk)) * 8);
      f16x8 a1 = *(const f16x8*)(asrc + ((kk + 1) * 64 + (lane ^ (kk + 1))) * 8);
      acc0 = __builtin_amdgcn_mfma_f32_16x16x32_f16(a0, bW[kk], acc0, 0, 0, 0);
      acc1 =
          __builtin_amdgcn_mfma_f32_16x16x32_f16(a1, bW[kk + 1], acc1, 0, 0, 0);
    }
#pragma unroll
    for (int r = 0; r < 4; ++r)
      gbuf[wave * 272 + (q * 4 + r) * 17 + n16] = acc0[r] + acc1[r];
    __syncthreads();

    // ---- Epilogue (fp32): gates, cell, highway, mask.
    if (tid < 128) {
      float g0 = gbuf[0 * 272 + eb * 17 + en] + 2.f * bb0;      // i
      float g1 = gbuf[0 * 272 + eb * 17 + en + 8] + 2.f * bb1;  // f
      float g2 = gbuf[1 * 272 + eb * 17 + en] + 2.f * bb2;      // m~
      float g3 = gbuf[1 * 272 + eb * 17 + en + 8] + 2.f * bb3;  // o
      float g4 = gbuf[2 * 272 + eb * 17 + en] + 2.f * bb4;      // hw
      float p5 = gbuf[2 * 272 + eb * 17 + en + 8];              // (x+h)@W5
      float qv = gbuf[3 * 272 + eb * 17 + en];                  // h@W5
      float ig = sigf(g0), fg = sigf(g1), mt = tanhfast(g2);
      float og = sigf(g3), hwv = sigf(g4);
      float pi5 = p5 - qv + bb5;
      float cold = cbuf[tid];
      float mem = ig * mt + fg * cold;
      float o1 = og * tanhfast(mem);
      float ov = hwv * o1 + (1.0f - hwv) * pi5;
      float msk = (t < mylen) ? 1.0f : 0.0f;
      ov *= msk;
      mem *= msk;
      cbuf[tid] = mem;
      out[((size_t)eb * TT + t) * HHH + wg * CC + en] = ov;
      obuf[tid] = (f16)ov;
    }
    __syncthreads();

    // ---- Publish h(t+1): packed tagged u64, relaxed agent atomics.
    if (tid < 64) {
      int m = tid >> 2, pp = tid & 3;
      unsigned short c0 = __builtin_bit_cast(unsigned short, obuf[m * 8 + 2 * pp]);
      unsigned short c1 =
          __builtin_bit_cast(unsigned short, obuf[m * 8 + 2 * pp + 1]);
      u64 wv = (u64)c0 | ((u64)c1 << 16) | ((u64)(unsigned)(t + 1) << 32);
      __hip_atomic_store(hex + (size_t)((t + 1) & 1) * 4096 + m * 256 + wg * 4 + pp,
                         wv, __ATOMIC_RELAXED, __HIP_MEMORY_SCOPE_AGENT);
    }

    // Prefetch x(t+1); latency hides under next step's tag polling.
    if (t + 1 < TT) {
#pragma unroll
      for (int i = 0; i < 8; ++i)
        xv[i] = *(const f32x4*)(x + xcm[i] + (size_t)(t + 1) * DD);
    }
  }
}

extern "C" void kernel_launch(void* const* d_in, const int* in_sizes, int n_in,
                              void* d_out, int out_size, void* d_ws,
                              size_t ws_size, hipStream_t stream) {
  (void)in_sizes;
  (void)n_in;
  (void)out_size;
  (void)ws_size;
  const float* x = (const float*)d_in[0];
  const int* lengths = (const int*)d_in[1];
  const float* W = (const float*)d_in[2];
  const float* bias = (const float*)d_in[3];
  float* out = (float*)d_out;

  u64* hex = (u64*)d_ws;  // [2][16][256] tagged pairs = 64 KB
  hipMemsetAsync(d_ws, 0, 2 * 4096 * sizeof(u64), stream);  // h0=0, tag=0

  lstm_scan<<<dim3(NG), dim3(BLK), 0, stream>>>(x, lengths, W, bias, out, hex);
}

// Round 3
// 7442.924 us; speedup vs baseline: 2.8168x; 1.3472x over previous
//
#include <hip/hip_runtime.h>

// AugmentedLstm: B=16, T=2048, D=H=512.
// 64 persistent WGs x 256 threads. No grid barrier: h' published as packed
// u64 agent-scope relaxed atomics {2 x f16, u32 step-tag}; consumers poll
// tags. Round 3: BATCHED re-poll (all 16 loads re-issued in parallel per
// round — round 2 had 16 sequential dependent spin loops = 16 IC round
// trips/step), direct publish from epilogue lanes via shfl_xor (drops obuf
// + one __syncthreads), 4 independent MFMA chains.
//
// Math: g = (x_t + h)@Wt[:, :5H] + 2b  (pi and ps share W)
//       pi5 = (x+h)@W5 - h@W5 + b5     (highway input)

#define NG 64
#define BLK 256
#define BB 16
#define TT 2048
#define DD 512
#define HHH 512
#define CC 8

typedef _Float16 f16;
typedef _Float16 f16x4 __attribute__((ext_vector_type(4)));
typedef _Float16 f16x8 __attribute__((ext_vector_type(8)));
typedef float f32x4 __attribute__((ext_vector_type(4)));
typedef unsigned long long u64;

__device__ __forceinline__ float sigf(float v) {
  return 1.0f / (1.0f + __expf(-v));
}
__device__ __forceinline__ float tanhfast(float v) {
  return 2.0f / (1.0f + __expf(-2.0f * v)) - 1.0f;
}

__device__ __forceinline__ f16 h_lo(u64 w) {
  return __builtin_bit_cast(f16, (unsigned short)(w & 0xffffu));
}
__device__ __forceinline__ f16 h_hi(u64 w) {
  return __builtin_bit_cast(f16, (unsigned short)((w >> 16) & 0xffffu));
}

__global__ __launch_bounds__(BLK, 1) void lstm_scan(
    const float* __restrict__ x, const int* __restrict__ lengths,
    const float* __restrict__ W, const float* __restrict__ bias,
    float* __restrict__ out, u64* __restrict__ hex /* [2][16][256] tagged */) {
  __shared__ f16 u_sw[BB * DD];        // u = x+h, swizzled A-frag order
  __shared__ f16 h_sw[BB * DD];        // h alone (for h@W5)
  __shared__ float gbuf[4 * 16 * 17];  // per-tile MFMA results
  __shared__ float cbuf[BB * CC];      // cell state

  const int tid = threadIdx.x;
  const int wg = blockIdx.x;
  const int wave = tid >> 6;
  const int lane = tid & 63;
  const int q = lane >> 4;
  const int n16 = lane & 15;

  // ---- Weight B-fragments in registers (loaded once).
  // Tiles 0..2: A=u, 16 cols = gates {0,1},{2,3},{4,5} x 8 cols.
  // Tile  3   : A=h, cols 0..7 = gate-5 rows (h@W5), cols 8..15 zero.
  f16x8 bW[16];
  {
    int grow = 0;
    bool valid = true;
    if (wave < 3) {
      int gate = 2 * wave + (n16 >> 3);
      grow = gate * HHH + wg * CC + (n16 & 7);
    } else if (n16 < 8) {
      grow = 5 * HHH + wg * CC + n16;
    } else {
      valid = false;
    }
    const float* wr = W + (size_t)grow * DD;
#pragma unroll
    for (int kk = 0; kk < 16; ++kk) {
      f16x8 v;
      if (valid) {
        const float* p = wr + kk * 32 + q * 8;
#pragma unroll
        for (int j = 0; j < 8; ++j) v[j] = (f16)p[j];
      } else {
#pragma unroll
        for (int j = 0; j < 8; ++j) v[j] = (f16)0.0f;
      }
      bW[kk] = v;
    }
  }

  // ---- Staging indices. Thread's i-th chunk = cols k..k+3 of row m of the
  // flat [16][512] matrix. LDS granule (8 f16): logical (kk*64 + L),
  // physical (kk*64 + (L ^ kk)) — XOR swizzle keeps ds_write at the 4-way
  // floor and ds_read_b128 conflict-free.
  int soffv[8], pidx[8];
  size_t xcm[8];
#pragma unroll
  for (int i = 0; i < 8; ++i) {
    int e = (tid + i * BLK) * 4;
    int m = e >> 9;
    int k = e & 511;
    pidx[i] = m * 256 + (k >> 1);      // u64 pair index (k multiple of 4)
    xcm[i] = (size_t)m * TT * DD + k;  // x[b=m][t][k] base
    int kk = k >> 5, qq = (k >> 3) & 3, j0 = k & 7;
    int L = qq * 16 + m;
    soffv[i] = (kk * 64 + (L ^ kk)) * 8 + j0;
  }

  // ---- Epilogue constants (threads 0..127: b = tid>>3, n = tid&7).
  const int eb = tid >> 3;
  const int en = tid & 7;
  float bb0 = 0, bb1 = 0, bb2 = 0, bb3 = 0, bb4 = 0, bb5 = 0;
  int mylen = 0;
  if (tid < 128) {
    int gc = wg * CC + en;
    bb0 = bias[0 * HHH + gc];
    bb1 = bias[1 * HHH + gc];
    bb2 = bias[2 * HHH + gc];
    bb3 = bias[3 * HHH + gc];
    bb4 = bias[4 * HHH + gc];
    bb5 = bias[5 * HHH + gc];
    mylen = lengths[eb];
    cbuf[tid] = 0.0f;
  }

  // Prefetch x(t=0).
  f32x4 xv[8];
#pragma unroll
  for (int i = 0; i < 8; ++i) xv[i] = *(const f32x4*)(x + xcm[i]);

  __syncthreads();

  for (int t = 0; t < TT; ++t) {
    // ---- Poll h(t): tag == t in parity slot t&1. Every round re-issues
    // ALL 16 loads in parallel (one IC round-trip per round), then checks.
    const u64* hb = hex + (size_t)(t & 1) * 4096;
    const unsigned wtag = (unsigned)t;
    u64 w0[8], w1[8];
    for (;;) {
#pragma unroll
      for (int i = 0; i < 8; ++i) {
        w0[i] = __hip_atomic_load(hb + pidx[i], __ATOMIC_RELAXED,
                                  __HIP_MEMORY_SCOPE_AGENT);
        w1[i] = __hip_atomic_load(hb + pidx[i] + 1, __ATOMIC_RELAXED,
                                  __HIP_MEMORY_SCOPE_AGENT);
      }
      unsigned bad = 0;
#pragma unroll
      for (int i = 0; i < 8; ++i)
        bad |= ((unsigned)(w0[i] >> 32) ^ wtag) |
               ((unsigned)(w1[i] >> 32) ^ wtag);
      if (bad == 0) break;
    }

    // ---- Stage u = f16(x)+h and h into LDS (swizzled).
#pragma unroll
    for (int i = 0; i < 8; ++i) {
      f16x4 hv;
      hv[0] = h_lo(w0[i]);
      hv[1] = h_hi(w0[i]);
      hv[2] = h_lo(w1[i]);
      hv[3] = h_hi(w1[i]);
      f16x4 uv;
#pragma unroll
      for (int j = 0; j < 4; ++j) uv[j] = (f16)xv[i][j] + hv[j];
      *(f16x4*)(u_sw + soffv[i]) = uv;
      *(f16x4*)(h_sw + soffv[i]) = hv;
    }
    __syncthreads();

    // ---- MFMA: wave's 16-col tile, K=512, 4 independent chains.
    f32x4 acc0 = {0.f, 0.f, 0.f, 0.f}, acc1 = {0.f, 0.f, 0.f, 0.f};
    f32x4 acc2 = {0.f, 0.f, 0.f, 0.f}, acc3 = {0.f, 0.f, 0.f, 0.f};
    const f16* asrc = (wave < 3) ? u_sw : h_sw;
#pragma unroll
    for (int kk = 0; kk < 16; kk += 4) {
      f16x8 a0 = *(const f16x8*)(asrc + (kk * 64 + (lane ^ kk)) * 8);
      f16x8 a1 =
          *(const f16x8*)(asrc + ((kk + 1) * 64 + (lane ^ (kk + 1))) * 8);
      f16x8 a2 =
          *(const f16x8*)(asrc + ((kk + 2) * 64 + (lane ^ (kk + 2))) * 8);
      f16x8 a3 =
          *(const f16x8*)(asrc + ((kk + 3) * 64 + (lane ^ (kk + 3))) * 8);
      acc0 = __builtin_amdgcn_mfma_f32_16x16x32_f16(a0, bW[kk], acc0, 0, 0, 0);
      acc1 =
          __builtin_amdgcn_mfma_f32_16x16x32_f16(a1, bW[kk + 1], acc1, 0, 0, 0);
      acc2 =
          __builtin_amdgcn_mfma_f32_16x16x32_f16(a2, bW[kk + 2], acc2, 0, 0, 0);
      acc3 =
          __builtin_amdgcn_mfma_f32_16x16x32_f16(a3, bW[kk + 3], acc3, 0, 0, 0);
    }
#pragma unroll
    for (int r = 0; r < 4; ++r)
      gbuf[wave * 272 + (q * 4 + r) * 17 + n16] =
          (acc0[r] + acc1[r]) + (acc2[r] + acc3[r]);
    __syncthreads();

    // ---- Epilogue (fp32) + direct publish (waves 0-1; partner via shfl).
    if (tid < 128) {
      float g0 = gbuf[0 * 272 + eb * 17 + en] + 2.f * bb0;      // i
      float g1 = gbuf[0 * 272 + eb * 17 + en + 8] + 2.f * bb1;  // f
      float g2 = gbuf[1 * 272 + eb * 17 + en] + 2.f * bb2;      // m~
      float g3 = gbuf[1 * 272 + eb * 17 + en + 8] + 2.f * bb3;  // o
      float g4 = gbuf[2 * 272 + eb * 17 + en] + 2.f * bb4;      // hw
      float p5 = gbuf[2 * 272 + eb * 17 + en + 8];              // (x+h)@W5
      float qv = gbuf[3 * 272 + eb * 17 + en];                  // h@W5
      float ig = sigf(g0), fg = sigf(g1), mt = tanhfast(g2);
      float og = sigf(g3), hwv = sigf(g4);
      float pi5 = p5 - qv + bb5;
      float cold = cbuf[tid];
      float mem = ig * mt + fg * cold;
      float o1 = og * tanhfast(mem);
      float ov = hwv * o1 + (1.0f - hwv) * pi5;
      float msk = (t < mylen) ? 1.0f : 0.0f;
      ov *= msk;
      mem *= msk;
      cbuf[tid] = mem;
      out[((size_t)eb * TT + t) * HHH + wg * CC + en] = ov;

      unsigned hbits =
          (unsigned)__builtin_bit_cast(unsigned short, (f16)ov);
      unsigned other = (unsigned)__shfl_xor((int)hbits, 1, 64);
      if ((en & 1) == 0) {
        u64 wv = (u64)(hbits & 0xffffu) | ((u64)(other & 0xffffu) << 16) |
                 ((u64)(unsigned)(t + 1) << 32);
        __hip_atomic_store(
            hex + (size_t)((t + 1) & 1) * 4096 + eb * 256 + wg * 4 + (en >> 1),
            wv, __ATOMIC_RELAXED, __HIP_MEMORY_SCOPE_AGENT);
      }
    }

    // Prefetch x(t+1); latency hides under next step's tag polling.
    if (t + 1 < TT) {
#pragma unroll
      for (int i = 0; i < 8; ++i)
        xv[i] = *(const f32x4*)(x + xcm[i] + (size_t)(t + 1) * DD);
    }
    // No trailing __syncthreads: next-step staging only touches u_sw/h_sw,
    // whose step-t reads all completed before the post-MFMA barrier; gbuf
    // writes for t+1 are fenced by the next post-staging barrier, which
    // cannot be reached before this WG's own publish (poll includes own
    // columns).
  }
}

extern "C" void kernel_launch(void* const* d_in, const int* in_sizes, int n_in,
                              void* d_out, int out_size, void* d_ws,
                              size_t ws_size, hipStream_t stream) {
  (void)in_sizes;
  (void)n_in;
  (void)out_size;
  (void)ws_size;
  const float* x = (const float*)d_in[0];
  const int* lengths = (const int*)d_in[1];
  const float* W = (const float*)d_in[2];
  const float* bias = (const float*)d_in[3];
  float* out = (float*)d_out;

  u64* hex = (u64*)d_ws;  // [2][16][256] tagged pairs = 64 KB
  hipMemsetAsync(d_ws, 0, 2 * 4096 * sizeof(u64), stream);  // h0=0, tag=0

  lstm_scan<<<dim3(NG), dim3(BLK), 0, stream>>>(x, lengths, W, bias, out, hex);
}